// Round 4
// baseline (1331.464 us; speedup 1.0000x reference)
//
#include <hip/hip_runtime.h>

typedef unsigned short ushortT;
typedef __attribute__((ext_vector_type(8))) short short8;
typedef __attribute__((ext_vector_type(4))) float float4v;

__device__ __forceinline__ float bf2f(unsigned short h) {
    unsigned u = ((unsigned)h) << 16;
    return __builtin_bit_cast(float, u);
}
__device__ __forceinline__ unsigned short f2bf(float f) {
    unsigned u = __builtin_bit_cast(unsigned, f);
    u = u + 0x7fffu + ((u >> 16) & 1u);
    return (unsigned short)(u >> 16);
}

// ---------------- f32 -> bf16 cast (weights) ----------------

__global__ __launch_bounds__(256) void cast_f32_bf16(const float* __restrict__ in, ushortT* __restrict__ out, int n4) {
    int i = blockIdx.x * 256 + threadIdx.x;
    if (i >= n4) return;
    float4 v = ((const float4*)in)[i];
    ushort4 o;
    o.x = f2bf(v.x); o.y = f2bf(v.y); o.z = f2bf(v.z); o.w = f2bf(v.w);
    ((ushort4*)out)[i] = o;
}

// ---------------- CSR build ----------------

__global__ __launch_bounds__(256) void zero_ints(int* p, int n) {
    int i = blockIdx.x * 256 + threadIdx.x;
    if (i < n) p[i] = 0;
}

__global__ __launch_bounds__(256) void hist_kernel(const int* __restrict__ dst, int* __restrict__ cnt, int E, int n) {
    int e = blockIdx.x * 256 + threadIdx.x;
    if (e < E) {
        int d = dst[e];
        if ((unsigned)d < (unsigned)n) atomicAdd(&cnt[d], 1);
    }
}

__device__ __forceinline__ int wave_incl_scan(int v, int lane) {
    #pragma unroll
    for (int d = 1; d < 64; d <<= 1) {
        int o = __shfl_up(v, d);
        if (lane >= d) v += o;
    }
    return v;
}

__global__ __launch_bounds__(256) void scanA(const int* __restrict__ cnt, int* __restrict__ out,
                                             int* __restrict__ bsum, int n) {
    __shared__ int wtot[4];
    int tid = threadIdx.x, blk = blockIdx.x;
    int base = blk * 1024 + tid * 4;
    int e[4];
    #pragma unroll
    for (int j = 0; j < 4; j++) { int idx = base + j; e[j] = (idx < n) ? cnt[idx] : 0; }
    int s = e[0] + e[1] + e[2] + e[3];
    int lane = tid & 63, w = tid >> 6;
    int incl = wave_incl_scan(s, lane);
    if (lane == 63) wtot[w] = incl;
    __syncthreads();
    int woff = 0;
    for (int i = 0; i < w; i++) woff += wtot[i];
    int run = woff + incl - s;
    #pragma unroll
    for (int j = 0; j < 4; j++) { int idx = base + j; if (idx < n) out[idx] = run; run += e[j]; }
    if (tid == 0) bsum[blk] = wtot[0] + wtot[1] + wtot[2] + wtot[3];
}

__global__ __launch_bounds__(64) void scanB(int* bsum, int nb) {
    int lane = threadIdx.x;
    int carry = 0;
    for (int base = 0; base < nb; base += 64) {
        int i = base + lane;
        int v = (i < nb) ? bsum[i] : 0;
        int incl = wave_incl_scan(v, lane);
        if (i < nb) bsum[i] = carry + incl - v;
        carry += __shfl(incl, 63);
    }
}

__global__ __launch_bounds__(256) void scanC(int* __restrict__ out, const int* __restrict__ bsum, int n, int E) {
    int blk = blockIdx.x, tid = threadIdx.x;
    int off = bsum[blk];
    int base = blk * 1024 + tid * 4;
    #pragma unroll
    for (int j = 0; j < 4; j++) { int idx = base + j; if (idx < n) out[idx] += off; }
    if (blk == 0 && tid == 0) out[n] = E;
}

__global__ __launch_bounds__(256) void dinv_cur_kernel(const int* __restrict__ rowptr, float* __restrict__ dinv,
                                                       int* __restrict__ cur, int n) {
    int i = blockIdx.x * 256 + threadIdx.x;
    if (i < n) {
        int deg = rowptr[i + 1] - rowptr[i] + 1;  // +1 self loop
        dinv[i] = rsqrtf((float)max(deg, 1));
        cur[i] = rowptr[i];
    }
}

__global__ __launch_bounds__(256) void fill_kernel(const int* __restrict__ src, const int* __restrict__ dst,
                                                   int* __restrict__ cur, int* __restrict__ colv, int E, int n) {
    int e = blockIdx.x * 256 + threadIdx.x;
    if (e < E) {
        int d = dst[e];
        if ((unsigned)d < (unsigned)n) {
            int p = atomicAdd(&cur[d], 1);
            colv[p] = src[e];
        }
    }
}

// ---------------- fused FastKAN transform ----------------
// Input row = concat of NSEG 128-wide segments; F32MASK bit s => segment s is f32 (else bf16).
// A = [rbf(LN(x)) | silu(x)]  [64rows x 5*DIN],  B = [Ws^T ; Wb^T] (bf16), H = A@B + bs + bb
template <int NSEG, int DOUT, int F32MASK>
__global__ __launch_bounds__(256) void fkan_kernel(
    const void* __restrict__ X0, int s0,
    const void* __restrict__ X1, int s1,
    const void* __restrict__ X2, int s2,
    const float* __restrict__ lng, const float* __restrict__ lnb,
    const ushortT* __restrict__ Wsb, const ushortT* __restrict__ Wbb,
    const float* __restrict__ bs, const float* __restrict__ bb,
    ushortT* __restrict__ H, int hstride, int nrows) {
    constexpr int DIN = NSEG * 128;
    constexpr int NT = (DOUT + 15) / 16;
    constexpr int LSTR = DIN + 8;  // +16B pad; rows stay 16B aligned
    __shared__ __align__(16) ushortT xs[64 * LSTR];

    int tid = threadIdx.x;
    int base = blockIdx.x * 64;

    constexpr int CHROW = NSEG * 16;  // 16B (8-elem) LDS chunks per row
    for (int idx = tid; idx < 64 * CHROW; idx += 256) {
        int r = idx / CHROW, cc = idx % CHROW;
        int seg = cc >> 4, c = (cc & 15) * 8;
        int row = base + r;
        const void* Xp = (seg == 0) ? X0 : (seg == 1) ? X1 : X2;
        int str = (seg == 0) ? s0 : (seg == 1) ? s1 : s2;
        uint4 v = make_uint4(0u, 0u, 0u, 0u);
        if (row < nrows) {
            if ((F32MASK >> seg) & 1) {
                const float* p = (const float*)Xp + (size_t)row * str + c;
                float4 a = *(const float4*)p;
                float4 b = *(const float4*)(p + 4);
                v.x = (unsigned)f2bf(a.x) | ((unsigned)f2bf(a.y) << 16);
                v.y = (unsigned)f2bf(a.z) | ((unsigned)f2bf(a.w) << 16);
                v.z = (unsigned)f2bf(b.x) | ((unsigned)f2bf(b.y) << 16);
                v.w = (unsigned)f2bf(b.z) | ((unsigned)f2bf(b.w) << 16);
            } else {
                v = *(const uint4*)((const ushortT*)Xp + (size_t)row * str + c);
            }
        }
        *(uint4*)(&xs[r * LSTR + seg * 128 + c]) = v;
    }
    __syncthreads();

    int w = tid >> 6, lane = tid & 63;
    int m = lane & 15, q = lane >> 4;
    int lr = w * 16 + m;
    const ushortT* xrow = &xs[lr * LSTR];

    // LayerNorm stats: each quad sums a quarter of the row, combine via shfl_xor
    float sum = 0.f, ssq = 0.f;
    constexpr int QC = DIN / 4;
    for (int c = q * QC; c < (q + 1) * QC; c += 2) {
        unsigned v = *(const unsigned*)(xrow + c);
        float a = bf2f((unsigned short)v), b2 = bf2f((unsigned short)(v >> 16));
        sum += a + b2;
        ssq += a * a + b2 * b2;
    }
    sum += __shfl_xor(sum, 16); ssq += __shfl_xor(ssq, 16);
    sum += __shfl_xor(sum, 32); ssq += __shfl_xor(ssq, 32);
    float mu = sum * (1.0f / DIN);
    float var = ssq * (1.0f / DIN) - mu * mu;
    float sc = rsqrtf(fmaxf(var, 0.0f) + 1e-5f);

    float4v acc[NT];
    #pragma unroll
    for (int t = 0; t < NT; t++) acc[t] = (float4v){0.f, 0.f, 0.f, 0.f};

    for (int ks = 0; ks < 5 * DIN; ks += 32) {
        short8 af;
        if (ks < 4 * DIN) {
            // RBF region: A col k = 4*din_idx + g; this lane: din cols c0,c0+1, grids 0..3
            int c0 = (ks >> 2) + 2 * q;
            unsigned xv = *(const unsigned*)(xrow + c0);
            float x0 = bf2f((unsigned short)xv), x1 = bf2f((unsigned short)(xv >> 16));
            float g0 = lng[c0], g1 = lng[c0 + 1];
            float b0 = lnb[c0], b1 = lnb[c0 + 1];
            float z0 = (x0 - mu) * sc * g0 + b0;
            float z1 = (x1 - mu) * sc * g1 + b1;
            const float gr0 = -2.f, gr1 = -2.f / 3.f, gr2 = 2.f / 3.f, gr3 = 2.f;
            #pragma unroll
            for (int j = 0; j < 8; j++) {
                float z = (j < 4) ? z0 : z1;
                float g = (j & 3) == 0 ? gr0 : (j & 3) == 1 ? gr1 : (j & 3) == 2 ? gr2 : gr3;
                float t0 = (z - g) * 0.75f;  // 1/DENOM = 3/4
                float f = __expf(-t0 * t0);
                af[j] = (short)f2bf(f);
            }
        } else {
            // base region: silu(x) on 8 consecutive cols
            int cb = (ks - 4 * DIN) + q * 8;
            uint4 xv = *(const uint4*)(xrow + cb);
            unsigned uu[4] = {xv.x, xv.y, xv.z, xv.w};
            #pragma unroll
            for (int j = 0; j < 8; j++) {
                unsigned short hb = (unsigned short)(uu[j >> 1] >> ((j & 1) * 16));
                float xf = bf2f(hb);
                float sg = 1.0f / (1.0f + __expf(-xf));
                af[j] = (short)f2bf(xf * sg);
            }
        }
        #pragma unroll
        for (int t = 0; t < NT; t++) {
            int n = t * 16 + m;
            short8 bfr = (short8){0, 0, 0, 0, 0, 0, 0, 0};
            bool ok = (DOUT % 16 == 0) || (n < DOUT);
            if (ok) {
                const ushortT* bp;
                if (ks < 4 * DIN) bp = Wsb + (size_t)n * (4 * DIN) + ks + q * 8;
                else              bp = Wbb + (size_t)n * DIN + (ks - 4 * DIN) + q * 8;
                bfr = *(const short8*)bp;
            }
            acc[t] = __builtin_amdgcn_mfma_f32_16x16x32_bf16(af, bfr, acc[t], 0, 0, 0);
        }
    }

    // epilogue: C/D layout col=lane&15, row=quad*4+r
    #pragma unroll
    for (int t = 0; t < NT; t++) {
        int col = t * 16 + m;
        if ((DOUT % 16 == 0) || (col < DOUT)) {
            float bias = bs[col] + bb[col];
            #pragma unroll
            for (int r = 0; r < 4; r++) {
                int row = base + w * 16 + q * 4 + r;
                if (row < nrows) H[(size_t)row * hstride + col] = f2bf(acc[t][r] + bias);
            }
        }
    }
}

// ---------------- aggregation (wave per node, CSR gather) ----------------

__global__ __launch_bounds__(256) void agg128_kernel(
    const ushortT* __restrict__ H, int hs, ushortT* __restrict__ OUT, int os,
    const float* __restrict__ bg, const int* __restrict__ rowptr,
    const int* __restrict__ colv, const float* __restrict__ dinv, int n) {
    int wid = (blockIdx.x * 256 + threadIdx.x) >> 6;
    int lane = threadIdx.x & 63;
    if (wid >= n) return;
    int c = lane * 2;
    float di = dinv[wid];
    unsigned hv = *(const unsigned*)(H + (size_t)wid * hs + c);
    float wself = di * di;
    float a0 = wself * bf2f((unsigned short)hv);
    float a1 = wself * bf2f((unsigned short)(hv >> 16));
    int e0 = rowptr[wid], e1 = rowptr[wid + 1];
    for (int e = e0; e < e1; ++e) {
        int s = colv[e];
        if ((unsigned)s >= (unsigned)n) continue;
        float wgt = dinv[s] * di;
        unsigned v = *(const unsigned*)(H + (size_t)s * hs + c);
        a0 += wgt * bf2f((unsigned short)v);
        a1 += wgt * bf2f((unsigned short)(v >> 16));
    }
    a0 += bg[c];
    a1 += bg[c + 1];
    unsigned outv = (unsigned)f2bf(a0) | ((unsigned)f2bf(a1) << 16);
    *(unsigned*)(OUT + (size_t)wid * os + c) = outv;
}

__global__ __launch_bounds__(256) void agg47_kernel(
    const ushortT* __restrict__ H, float* __restrict__ OUT,
    const float* __restrict__ bg, const int* __restrict__ rowptr,
    const int* __restrict__ colv, const float* __restrict__ dinv, int n) {
    int wid = (blockIdx.x * 256 + threadIdx.x) >> 6;
    int lane = threadIdx.x & 63;
    if (wid >= n) return;
    bool act = lane < 47;
    float di = dinv[wid];
    float acc = 0.f;
    if (act) acc = di * di * bf2f(H[(size_t)wid * 47 + lane]);
    int e0 = rowptr[wid], e1 = rowptr[wid + 1];
    for (int e = e0; e < e1; ++e) {
        int s = colv[e];
        if ((unsigned)s >= (unsigned)n) continue;
        float wgt = dinv[s] * di;
        if (act) acc += wgt * bf2f(H[(size_t)s * 47 + lane]);
    }
    if (act) OUT[(size_t)wid * 47 + lane] = acc + bg[lane];
}

// ---------------- launcher ----------------

extern "C" void kernel_launch(void* const* d_in, const int* in_sizes, int n_in,
                              void* d_out, int out_size, void* d_ws, size_t ws_size,
                              hipStream_t stream) {
    const float* x = (const float*)d_in[0];
    const int* ei = (const int*)d_in[1];
    const float* lng0 = (const float*)d_in[2];
    const float* lnb0 = (const float*)d_in[3];
    const float* Ws0 = (const float*)d_in[4];
    const float* bs0 = (const float*)d_in[5];
    const float* Wb0 = (const float*)d_in[6];
    const float* bb0 = (const float*)d_in[7];
    const float* bg0 = (const float*)d_in[8];
    const float* lng1 = (const float*)d_in[9];
    const float* lnb1 = (const float*)d_in[10];
    const float* Ws1 = (const float*)d_in[11];
    const float* bs1 = (const float*)d_in[12];
    const float* Wb1 = (const float*)d_in[13];
    const float* bb1 = (const float*)d_in[14];
    const float* bg1 = (const float*)d_in[15];
    const float* lng2 = (const float*)d_in[16];
    const float* lnb2 = (const float*)d_in[17];
    const float* Ws2 = (const float*)d_in[18];
    const float* bs2 = (const float*)d_in[19];
    const float* Wb2 = (const float*)d_in[20];
    const float* bb2 = (const float*)d_in[21];
    const float* bg2 = (const float*)d_in[22];

    const int N = in_sizes[0] / 128;
    const int E = in_sizes[1] / 2;

    char* wsp = (char*)d_ws;
    size_t off = 0;
    auto alloc = [&](size_t bytes) {
        off = (off + 255) & ~(size_t)255;
        void* p = wsp + off;
        off += bytes;
        return p;
    };
    int* cur = (int*)alloc((size_t)N * 4);
    int* rowptr = (int*)alloc((size_t)(N + 1) * 4);
    int* bsum = (int*)alloc(1024 * 4);
    int* colv = (int*)alloc((size_t)E * 4);
    float* dinvv = (float*)alloc((size_t)N * 4);
    ushortT* hbuf = (ushortT*)alloc((size_t)N * 128 * 2);
    ushortT* a1 = (ushortT*)alloc((size_t)N * 128 * 2);
    ushortT* a2 = (ushortT*)alloc((size_t)N * 128 * 2);
    ushortT* Wsb0 = (ushortT*)alloc((size_t)128 * 512 * 2);
    ushortT* Wbb0 = (ushortT*)alloc((size_t)128 * 128 * 2);
    ushortT* Wsb1 = (ushortT*)alloc((size_t)128 * 512 * 2);
    ushortT* Wbb1 = (ushortT*)alloc((size_t)128 * 128 * 2);
    ushortT* Wsb2 = (ushortT*)alloc((size_t)47 * 1536 * 2);
    ushortT* Wbb2 = (ushortT*)alloc((size_t)47 * 384 * 2);
    (void)n_in; (void)out_size; (void)ws_size;

    const int* srcp = ei;
    const int* dstp = ei + E;

    int gN = (N + 255) / 256;
    int gE = (E + 255) / 256;
    int nb = (N + 1023) / 1024;
    int gT = (N + 63) / 64;
    int gW = (N + 3) / 4;

    // weight casts (f32 -> bf16)
    auto cast = [&](const float* in, ushortT* out, int n) {
        int n4 = n / 4;
        cast_f32_bf16<<<(n4 + 255) / 256, 256, 0, stream>>>(in, out, n4);
    };
    cast(Ws0, Wsb0, 128 * 512);
    cast(Wb0, Wbb0, 128 * 128);
    cast(Ws1, Wsb1, 128 * 512);
    cast(Wb1, Wbb1, 128 * 128);
    cast(Ws2, Wsb2, 47 * 1536);
    cast(Wb2, Wbb2, 47 * 384);

    // CSR build
    zero_ints<<<gN, 256, 0, stream>>>(cur, N);
    hist_kernel<<<gE, 256, 0, stream>>>(dstp, cur, E, N);
    scanA<<<nb, 256, 0, stream>>>(cur, rowptr, bsum, N);
    scanB<<<1, 64, 0, stream>>>(bsum, nb);
    scanC<<<nb, 256, 0, stream>>>(rowptr, bsum, N, E);
    dinv_cur_kernel<<<gN, 256, 0, stream>>>(rowptr, dinvv, cur, N);
    fill_kernel<<<gE, 256, 0, stream>>>(srcp, dstp, cur, colv, E, N);

    // layer 1: x(f32) -> h, agg -> a1
    fkan_kernel<1, 128, 1><<<gT, 256, 0, stream>>>(x, 128, x, 128, x, 128,
                                                   lng0, lnb0, Wsb0, Wbb0, bs0, bb0, hbuf, 128, N);
    agg128_kernel<<<gW, 256, 0, stream>>>(hbuf, 128, a1, 128, bg0, rowptr, colv, dinvv, N);

    // layer 2: a1(bf16) -> h, agg -> a2
    fkan_kernel<1, 128, 0><<<gT, 256, 0, stream>>>(a1, 128, a1, 128, a1, 128,
                                                   lng1, lnb1, Wsb1, Wbb1, bs1, bb1, hbuf, 128, N);
    agg128_kernel<<<gW, 256, 0, stream>>>(hbuf, 128, a2, 128, bg1, rowptr, colv, dinvv, N);

    // layer 3: [x(f32) | a1 | a2] -> h[N,47], agg -> d_out (f32)
    fkan_kernel<3, 47, 1><<<gT, 256, 0, stream>>>(x, 128, a1, 128, a2, 128,
                                                  lng2, lnb2, Wsb2, Wbb2, bs2, bb2, hbuf, 47, N);
    agg47_kernel<<<gW, 256, 0, stream>>>(hbuf, (float*)d_out, bg2, rowptr, colv, dinvv, N);
}